// Round 1
// baseline (266.337 us; speedup 1.0000x reference)
//
#include <hip/hip_runtime.h>
#include <hip/hip_bf16.h>
#include <math.h>

// Causal attention, B=2 H=16 S=2048 D=64, fp32 in/out, bf16 MFMA compute.
// Flash-style: block = 4 waves = 64 q-rows of one head; 64-key tiles staged in LDS.

constexpr int S  = 2048;
constexpr int D  = 64;
constexpr int BH = 32;                 // B*H
constexpr float SCALE = 0.125f;        // 64^-0.5
constexpr float LOG2E = 1.4426950408889634f;
constexpr int BQ = 64, BK = 64, NW = 4;
constexpr int KSTR = 72;               // padded bf16 row stride: +16B keeps b128 align, breaks 16-way conflicts

typedef __attribute__((ext_vector_type(8))) short bf16x8;   // MFMA A/B frag (4 VGPRs)
typedef __attribute__((ext_vector_type(4))) short bf16x4;
typedef __attribute__((ext_vector_type(4))) float f32x4;    // MFMA C/D frag

__device__ __forceinline__ short f2bf(float x) {
    __hip_bfloat16 h = __float2bfloat16(x);
    union { __hip_bfloat16 b; short s; } u; u.b = h; return u.s;
}

__global__ __launch_bounds__(256) void attn_fwd_25993142075924(
    const float* __restrict__ Qg, const float* __restrict__ Kg,
    const float* __restrict__ Vg, float* __restrict__ Og)
{
    const int qt  = blockIdx.x;        // q-tile 0..31
    const int bh  = blockIdx.y;        // head 0..31
    const int tid = threadIdx.x;
    const int wv  = tid >> 6;          // wave 0..3
    const int ln  = tid & 63;
    const int c16 = ln & 15;           // MFMA: A-row / B-col / C-col
    const int qd  = ln >> 4;           // quad 0..3

    __shared__ __align__(16) __hip_bfloat16 lk [BK][KSTR];   // K tile, [key][d]
    __shared__ __align__(16) __hip_bfloat16 lvt[D ][KSTR];   // V^T tile, [d][key]
    __shared__ __align__(16) __hip_bfloat16 lp [NW][16][KSTR]; // per-wave P strip, [q][key]

    const size_t hoff = (size_t)bh * S * D;
    const float* qp = Qg + hoff;
    const float* kp = Kg + hoff;
    const float* vp = Vg + hoff;
    float*       op = Og + hoff;

    const int q0 = qt * BQ;

    // Q fragments: A[m=c16][k=qd*8+j], two K-halves (D=64 = 2*32)
    bf16x8 qf[2];
    {
        const float* src = qp + (size_t)(q0 + wv*16 + c16) * D + qd*8;
        #pragma unroll
        for (int kh = 0; kh < 2; ++kh) {
            f32x4 a = *(const f32x4*)(src + kh*32);
            f32x4 b = *(const f32x4*)(src + kh*32 + 4);
            bf16x8 f;
            f[0]=f2bf(a[0]); f[1]=f2bf(a[1]); f[2]=f2bf(a[2]); f[3]=f2bf(a[3]);
            f[4]=f2bf(b[0]); f[5]=f2bf(b[1]); f[6]=f2bf(b[2]); f[7]=f2bf(b[3]);
            qf[kh] = f;
        }
    }

    f32x4 oacc[4] = {{0,0,0,0},{0,0,0,0},{0,0,0,0},{0,0,0,0}};
    float mrun[4] = {-INFINITY,-INFINITY,-INFINITY,-INFINITY};
    float lrun[4] = {0.f,0.f,0.f,0.f};

    const int nkt = qt + 1;            // causal: only key tiles <= diagonal
    for (int kt = 0; kt < nkt; ++kt) {
        __syncthreads();               // protect previous tile's LDS reads
        // ---- stage K (row-major) and V^T into LDS, fp32 -> bf16 ----
        #pragma unroll
        for (int e = 0; e < 4; ++e) {
            int idx = (tid + e*256) * 4;        // flat float idx in 64x64 tile
            int row = idx >> 6, col = idx & 63;
            f32x4 k4 = *(const f32x4*)(kp + (size_t)(kt*BK + row)*D + col);
            bf16x4 kb;
            kb[0]=f2bf(k4[0]); kb[1]=f2bf(k4[1]); kb[2]=f2bf(k4[2]); kb[3]=f2bf(k4[3]);
            *(bf16x4*)&lk[row][col] = kb;
            f32x4 v4 = *(const f32x4*)(vp + (size_t)(kt*BK + row)*D + col);
            lvt[col+0][row] = __float2bfloat16(v4[0]);
            lvt[col+1][row] = __float2bfloat16(v4[1]);
            lvt[col+2][row] = __float2bfloat16(v4[2]);
            lvt[col+3][row] = __float2bfloat16(v4[3]);
        }
        __syncthreads();

        // ---- QK^T: 4 key-groups x 2 K-halves; t = score*SCALE*log2e ----
        float t[4][4];
        #pragma unroll
        for (int nt = 0; nt < 4; ++nt) {
            f32x4 acc = {0,0,0,0};
            #pragma unroll
            for (int kh = 0; kh < 2; ++kh) {
                bf16x8 kf = *(const bf16x8*)&lk[nt*16 + c16][kh*32 + qd*8];
                acc = __builtin_amdgcn_mfma_f32_16x16x32_bf16(qf[kh], kf, acc, 0, 0, 0);
            }
            #pragma unroll
            for (int r = 0; r < 4; ++r) t[nt][r] = acc[r] * (SCALE * LOG2E);
        }
        if (kt == nkt - 1) {           // diagonal tile: apply causal mask
            #pragma unroll
            for (int nt = 0; nt < 4; ++nt) {
                int j = kt*BK + nt*16 + c16;
                #pragma unroll
                for (int r = 0; r < 4; ++r) {
                    int i = q0 + wv*16 + qd*4 + r;
                    if (j > i) t[nt][r] = -INFINITY;
                }
            }
        }

        // ---- online softmax (row = qd*4+r, cols across 16-lane group) ----
        float pval[4][4];
        #pragma unroll
        for (int r = 0; r < 4; ++r) {
            float tm = fmaxf(fmaxf(t[0][r], t[1][r]), fmaxf(t[2][r], t[3][r]));
            tm = fmaxf(tm, __shfl_xor(tm, 1));
            tm = fmaxf(tm, __shfl_xor(tm, 2));
            tm = fmaxf(tm, __shfl_xor(tm, 4));
            tm = fmaxf(tm, __shfl_xor(tm, 8));
            float mnew  = fmaxf(mrun[r], tm);
            float alpha = exp2f(mrun[r] - mnew);   // first tile: exp2(-inf)=0
            mrun[r] = mnew;
            float rs = 0.f;
            #pragma unroll
            for (int nt = 0; nt < 4; ++nt) {
                float p = exp2f(t[nt][r] - mnew);  // masked: exp2(-inf)=0
                pval[nt][r] = p;
                rs += p;
            }
            rs += __shfl_xor(rs, 1);
            rs += __shfl_xor(rs, 2);
            rs += __shfl_xor(rs, 4);
            rs += __shfl_xor(rs, 8);
            lrun[r] = lrun[r] * alpha + rs;
            #pragma unroll
            for (int dt = 0; dt < 4; ++dt) oacc[dt][r] *= alpha;
        }

        // ---- P: C-layout -> row-major LDS -> A-layout frags (wave-local) ----
        #pragma unroll
        for (int nt = 0; nt < 4; ++nt)
            #pragma unroll
            for (int r = 0; r < 4; ++r)
                lp[wv][qd*4 + r][nt*16 + c16] = __float2bfloat16(pval[nt][r]);
        bf16x8 pf[2];
        #pragma unroll
        for (int kh = 0; kh < 2; ++kh)
            pf[kh] = *(const bf16x8*)&lp[wv][c16][kh*32 + qd*8];

        // ---- PV: O[q][d] += P[q][key] * V[key][d], B from V^T tile ----
        #pragma unroll
        for (int dt = 0; dt < 4; ++dt) {
            #pragma unroll
            for (int kh = 0; kh < 2; ++kh) {
                bf16x8 vf = *(const bf16x8*)&lvt[dt*16 + c16][kh*32 + qd*8];
                oacc[dt] = __builtin_amdgcn_mfma_f32_16x16x32_bf16(pf[kh], vf, oacc[dt], 0, 0, 0);
            }
        }
    }

    // ---- epilogue: O /= l, store fp32 (C-layout: row=qd*4+r, col=dt*16+c16) ----
    #pragma unroll
    for (int r = 0; r < 4; ++r) {
        float inv = 1.0f / lrun[r];
        int row = q0 + wv*16 + qd*4 + r;
        float* dst = op + (size_t)row * D;
        #pragma unroll
        for (int dt = 0; dt < 4; ++dt)
            dst[dt*16 + c16] = oacc[dt][r] * inv;
    }
}

extern "C" void kernel_launch(void* const* d_in, const int* in_sizes, int n_in,
                              void* d_out, int out_size, void* d_ws, size_t ws_size,
                              hipStream_t stream) {
    const float* q = (const float*)d_in[0];
    const float* k = (const float*)d_in[1];
    const float* v = (const float*)d_in[2];
    // d_in[3] = causal mask; causality is computed analytically, mask ignored.
    float* out = (float*)d_out;
    dim3 grid(S / BQ, BH, 1);
    dim3 block(256, 1, 1);
    hipLaunchKernelGGL(attn_fwd_25993142075924, grid, block, 0, stream, q, k, v, out);
}

// Round 2
// 227.024 us; speedup vs baseline: 1.1732x; 1.1732x over previous
//
#include <hip/hip_runtime.h>
#include <hip/hip_bf16.h>
#include <math.h>

// Causal attention, B=2 H=16 S=2048 D=64, fp32 in/out, bf16 MFMA compute.
// R2: pre-kernel converts K -> bf16 and V -> V^T bf16 into d_ws; attention
// hot loop stages tiles via global_load_lds dwordx4 with XOR-swizzled LDS
// layout (conflict-free unpadded power-of-2 tiles), Q pre-scaled by
// SCALE*log2e so MFMA output feeds exp2 directly.

constexpr int S  = 2048;
constexpr int D  = 64;
constexpr int BH = 32;                 // B*H
constexpr float SCALE = 0.125f;        // 64^-0.5
constexpr float LOG2E = 1.4426950408889634f;
constexpr float QPRE  = SCALE * LOG2E; // folded into Q before bf16 cvt
constexpr int BQ = 64, BK = 64, NW = 4;
constexpr int PSTR = 72;               // P strip stride (bf16): 144B rows, 16B-aligned, 2-way banks only

typedef __attribute__((ext_vector_type(8))) short bf16x8;   // MFMA A/B frag (4 VGPRs)
typedef __attribute__((ext_vector_type(4))) short bf16x4;
typedef __attribute__((ext_vector_type(4))) float f32x4;    // MFMA C/D frag

__device__ __forceinline__ short f2bf(float x) {
    union { __hip_bfloat16 b; short s; } u; u.b = __float2bfloat16(x); return u.s;
}

// async global->LDS, 16B per lane; lds base must be wave-uniform (lane slots auto)
__device__ __forceinline__ void gload_lds16(const void* g, void* lds) {
    __builtin_amdgcn_global_load_lds(
        (const __attribute__((address_space(1))) unsigned int*)g,
        (__attribute__((address_space(3))) unsigned int*)lds, 16, 0, 0);
}

// ---------------- pre-kernel: K fp32 -> bf16 copy; V fp32 -> V^T bf16 ----------------
__global__ __launch_bounds__(256) void preconv_25993142075924(
    const float* __restrict__ Kg, const float* __restrict__ Vg,
    short* __restrict__ Kb, short* __restrict__ VT)
{
    const int kt = blockIdx.x, bh = blockIdx.y, tid = threadIdx.x;
    __shared__ __align__(16) short lt[64 * PSTR];     // V tile transposed [d][key], padded
    const float* kp = Kg + (size_t)bh * S * D;
    const float* vp = Vg + (size_t)bh * S * D;
    short* kb = Kb + (size_t)bh * S * D;
    short* vt = VT + (size_t)bh * D * S;
    #pragma unroll
    for (int e = 0; e < 4; ++e) {
        int idx = (tid + e * 256) * 4;
        int r = idx >> 6, c = idx & 63;
        f32x4 k4 = *(const f32x4*)(kp + (size_t)(kt * 64 + r) * D + c);
        bf16x4 kb4;
        kb4[0] = f2bf(k4[0]); kb4[1] = f2bf(k4[1]);
        kb4[2] = f2bf(k4[2]); kb4[3] = f2bf(k4[3]);
        *(bf16x4*)(kb + (size_t)(kt * 64 + r) * D + c) = kb4;
        f32x4 v4 = *(const f32x4*)(vp + (size_t)(kt * 64 + r) * D + c);
        lt[(c + 0) * PSTR + r] = f2bf(v4[0]);
        lt[(c + 1) * PSTR + r] = f2bf(v4[1]);
        lt[(c + 2) * PSTR + r] = f2bf(v4[2]);
        lt[(c + 3) * PSTR + r] = f2bf(v4[3]);
    }
    __syncthreads();
    #pragma unroll
    for (int e = 0; e < 2; ++e) {
        int idx = tid + e * 256;
        int d = idx >> 3, kg = idx & 7;
        bf16x8 rowv = *(const bf16x8*)&lt[d * PSTR + kg * 8];
        *(bf16x8*)(vt + (size_t)d * S + kt * 64 + kg * 8) = rowv;
    }
}

// ---------------- main kernel (v2): bf16 K / V^T from ws ----------------
__global__ __launch_bounds__(256) void attn_fwd_v2_25993142075924(
    const float* __restrict__ Qg, const short* __restrict__ Kb,
    const short* __restrict__ VT, float* __restrict__ Og)
{
    const int qt  = blockIdx.x;
    const int bh  = blockIdx.y;
    const int tid = threadIdx.x;
    const int wv  = tid >> 6;
    const int ln  = tid & 63;
    const int c16 = ln & 15;
    const int qd  = ln >> 4;

    // swizzled tiles: physical slot (row, gphys) holds logical 16B-group gphys^(row&7)
    __shared__ __align__(16) short lk [BK * D];        // K tile  [key][d]
    __shared__ __align__(16) short lvt[D * BK];        // V^T tile [d][key]
    __shared__ __align__(16) short lp [NW * 16 * PSTR];// per-wave P strip [q][key]

    const float* qp = Qg + (size_t)bh * S * D;
    const short* kh_ = Kb + (size_t)bh * S * D;
    const short* vh_ = VT + (size_t)bh * D * S;
    float*       op = Og + (size_t)bh * S * D;
    const int q0 = qt * BQ;

    // Q fragments, pre-scaled: A[m=c16][k=qd*8+j]
    bf16x8 qf[2];
    {
        const float* src = qp + (size_t)(q0 + wv * 16 + c16) * D + qd * 8;
        #pragma unroll
        for (int khf = 0; khf < 2; ++khf) {
            f32x4 a = *(const f32x4*)(src + khf * 32);
            f32x4 b = *(const f32x4*)(src + khf * 32 + 4);
            bf16x8 f;
            f[0] = f2bf(a[0] * QPRE); f[1] = f2bf(a[1] * QPRE);
            f[2] = f2bf(a[2] * QPRE); f[3] = f2bf(a[3] * QPRE);
            f[4] = f2bf(b[0] * QPRE); f[5] = f2bf(b[1] * QPRE);
            f[6] = f2bf(b[2] * QPRE); f[7] = f2bf(b[3] * QPRE);
            qf[khf] = f;
        }
    }

    f32x4 oacc[4] = {{0,0,0,0},{0,0,0,0},{0,0,0,0},{0,0,0,0}};
    float mrun[4], lrun[4];
    #pragma unroll
    for (int r = 0; r < 4; ++r) { mrun[r] = -INFINITY; lrun[r] = 0.f; }

    short* lpw = lp + wv * 16 * PSTR;

    const int nkt = qt + 1;
    for (int kt = 0; kt < nkt; ++kt) {
        __syncthreads();               // prior tile's LDS reads done
        // ---- stage K + V^T via async 16B DMA, swizzle in the lane->global map ----
        #pragma unroll
        for (int ii = 0; ii < 2; ++ii) {
            int r0  = (wv * 2 + ii) * 8;          // 8 rows per instruction
            int row = r0 + (ln >> 3);
            int grp = (ln & 7) ^ (row & 7);
            gload_lds16(kh_ + (size_t)(kt * BK + row) * D + grp * 8, &lk[r0 * D]);
            gload_lds16(vh_ + (size_t)row * S + kt * BK + grp * 8, &lvt[r0 * D]);
        }
        __syncthreads();               // drains vmcnt -> DMA complete

        // ---- QK^T: t already in log2 domain (Q pre-scaled) ----
        float t[4][4];
        #pragma unroll
        for (int nt = 0; nt < 4; ++nt) {
            f32x4 acc = {0,0,0,0};
            int row = nt * 16 + c16;
            #pragma unroll
            for (int khf = 0; khf < 2; ++khf) {
                int g = (khf * 4 + qd) ^ (row & 7);
                bf16x8 kf = *(const bf16x8*)&lk[row * D + g * 8];
                acc = __builtin_amdgcn_mfma_f32_16x16x32_bf16(qf[khf], kf, acc, 0, 0, 0);
            }
            t[nt][0] = acc[0]; t[nt][1] = acc[1]; t[nt][2] = acc[2]; t[nt][3] = acc[3];
        }
        if (kt == nkt - 1) {           // diagonal tile: causal mask
            #pragma unroll
            for (int nt = 0; nt < 4; ++nt) {
                int j = kt * BK + nt * 16 + c16;
                #pragma unroll
                for (int r = 0; r < 4; ++r)
                    if (j > q0 + wv * 16 + qd * 4 + r) t[nt][r] = -INFINITY;
            }
        }

        // ---- online softmax (rows within 16-lane groups) ----
        float pval[4][4];
        #pragma unroll
        for (int r = 0; r < 4; ++r) {
            float tm = fmaxf(fmaxf(t[0][r], t[1][r]), fmaxf(t[2][r], t[3][r]));
            tm = fmaxf(tm, __shfl_xor(tm, 1));
            tm = fmaxf(tm, __shfl_xor(tm, 2));
            tm = fmaxf(tm, __shfl_xor(tm, 4));
            tm = fmaxf(tm, __shfl_xor(tm, 8));
            float mnew  = fmaxf(mrun[r], tm);
            float alpha = exp2f(mrun[r] - mnew);
            mrun[r] = mnew;
            float rs = 0.f;
            #pragma unroll
            for (int nt = 0; nt < 4; ++nt) {
                float p = exp2f(t[nt][r] - mnew);
                pval[nt][r] = p;
                rs += p;
            }
            rs += __shfl_xor(rs, 1);
            rs += __shfl_xor(rs, 2);
            rs += __shfl_xor(rs, 4);
            rs += __shfl_xor(rs, 8);
            lrun[r] = lrun[r] * alpha + rs;
            #pragma unroll
            for (int dt = 0; dt < 4; ++dt) oacc[dt][r] *= alpha;
        }

        // ---- P: C-layout -> wave-private LDS -> A-layout frags ----
        #pragma unroll
        for (int nt = 0; nt < 4; ++nt)
            #pragma unroll
            for (int r = 0; r < 4; ++r)
                lpw[(qd * 4 + r) * PSTR + nt * 16 + c16] = f2bf(pval[nt][r]);
        bf16x8 pf[2];
        #pragma unroll
        for (int khf = 0; khf < 2; ++khf)
            pf[khf] = *(const bf16x8*)&lpw[c16 * PSTR + khf * 32 + qd * 8];

        // ---- PV from swizzled V^T tile ----
        #pragma unroll
        for (int dt = 0; dt < 4; ++dt) {
            int row = dt * 16 + c16;
            #pragma unroll
            for (int khf = 0; khf < 2; ++khf) {
                int g = (khf * 4 + qd) ^ (row & 7);
                bf16x8 vf = *(const bf16x8*)&lvt[row * D + g * 8];
                oacc[dt] = __builtin_amdgcn_mfma_f32_16x16x32_bf16(pf[khf], vf, oacc[dt], 0, 0, 0);
            }
        }
    }

    // ---- epilogue ----
    #pragma unroll
    for (int r = 0; r < 4; ++r) {
        float inv = 1.0f / lrun[r];
        float* dst = op + (size_t)(q0 + wv * 16 + qd * 4 + r) * D;
        #pragma unroll
        for (int dt = 0; dt < 4; ++dt)
            dst[dt * 16 + c16] = oacc[dt][r] * inv;
    }
}

// ---------------- fallback (R1 kernel, fp32 inputs direct) ----------------
__global__ __launch_bounds__(256) void attn_fwd_v1_25993142075924(
    const float* __restrict__ Qg, const float* __restrict__ Kg,
    const float* __restrict__ Vg, float* __restrict__ Og)
{
    constexpr int KSTR = 72;
    const int qt  = blockIdx.x;
    const int bh  = blockIdx.y;
    const int tid = threadIdx.x;
    const int wv  = tid >> 6;
    const int ln  = tid & 63;
    const int c16 = ln & 15;
    const int qd  = ln >> 4;

    __shared__ __align__(16) __hip_bfloat16 lk [BK][KSTR];
    __shared__ __align__(16) __hip_bfloat16 lvt[D ][KSTR];
    __shared__ __align__(16) __hip_bfloat16 lp [NW][16][KSTR];

    const size_t hoff = (size_t)bh * S * D;
    const float* qp = Qg + hoff;
    const float* kp = Kg + hoff;
    const float* vp = Vg + hoff;
    float*       op = Og + hoff;
    const int q0 = qt * BQ;

    bf16x8 qf[2];
    {
        const float* src = qp + (size_t)(q0 + wv*16 + c16) * D + qd*8;
        #pragma unroll
        for (int kh = 0; kh < 2; ++kh) {
            f32x4 a = *(const f32x4*)(src + kh*32);
            f32x4 b = *(const f32x4*)(src + kh*32 + 4);
            bf16x8 f;
            f[0]=f2bf(a[0]*QPRE); f[1]=f2bf(a[1]*QPRE); f[2]=f2bf(a[2]*QPRE); f[3]=f2bf(a[3]*QPRE);
            f[4]=f2bf(b[0]*QPRE); f[5]=f2bf(b[1]*QPRE); f[6]=f2bf(b[2]*QPRE); f[7]=f2bf(b[3]*QPRE);
            qf[kh] = f;
        }
    }

    f32x4 oacc[4] = {{0,0,0,0},{0,0,0,0},{0,0,0,0},{0,0,0,0}};
    float mrun[4] = {-INFINITY,-INFINITY,-INFINITY,-INFINITY};
    float lrun[4] = {0.f,0.f,0.f,0.f};

    const int nkt = qt + 1;
    for (int kt = 0; kt < nkt; ++kt) {
        __syncthreads();
        #pragma unroll
        for (int e = 0; e < 4; ++e) {
            int idx = (tid + e*256) * 4;
            int row = idx >> 6, col = idx & 63;
            f32x4 k4 = *(const f32x4*)(kp + (size_t)(kt*BK + row)*D + col);
            bf16x4 kb;
            kb[0]=f2bf(k4[0]); kb[1]=f2bf(k4[1]); kb[2]=f2bf(k4[2]); kb[3]=f2bf(k4[3]);
            *(bf16x4*)&lk[row][col] = kb;
            f32x4 v4 = *(const f32x4*)(vp + (size_t)(kt*BK + row)*D + col);
            lvt[col+0][row] = __float2bfloat16(v4[0]);
            lvt[col+1][row] = __float2bfloat16(v4[1]);
            lvt[col+2][row] = __float2bfloat16(v4[2]);
            lvt[col+3][row] = __float2bfloat16(v4[3]);
        }
        __syncthreads();

        float t[4][4];
        #pragma unroll
        for (int nt = 0; nt < 4; ++nt) {
            f32x4 acc = {0,0,0,0};
            #pragma unroll
            for (int kh = 0; kh < 2; ++kh) {
                bf16x8 kf = *(const bf16x8*)&lk[nt*16 + c16][kh*32 + qd*8];
                acc = __builtin_amdgcn_mfma_f32_16x16x32_bf16(qf[kh], kf, acc, 0, 0, 0);
            }
            #pragma unroll
            for (int r = 0; r < 4; ++r) t[nt][r] = acc[r];
        }
        if (kt == nkt - 1) {
            #pragma unroll
            for (int nt = 0; nt < 4; ++nt) {
                int j = kt*BK + nt*16 + c16;
                #pragma unroll
                for (int r = 0; r < 4; ++r)
                    if (j > q0 + wv*16 + qd*4 + r) t[nt][r] = -INFINITY;
            }
        }

        float pval[4][4];
        #pragma unroll
        for (int r = 0; r < 4; ++r) {
            float tm = fmaxf(fmaxf(t[0][r], t[1][r]), fmaxf(t[2][r], t[3][r]));
            tm = fmaxf(tm, __shfl_xor(tm, 1));
            tm = fmaxf(tm, __shfl_xor(tm, 2));
            tm = fmaxf(tm, __shfl_xor(tm, 4));
            tm = fmaxf(tm, __shfl_xor(tm, 8));
            float mnew  = fmaxf(mrun[r], tm);
            float alpha = exp2f(mrun[r] - mnew);
            mrun[r] = mnew;
            float rs = 0.f;
            #pragma unroll
            for (int nt = 0; nt < 4; ++nt) {
                float p = exp2f(t[nt][r] - mnew);
                pval[nt][r] = p;
                rs += p;
            }
            rs += __shfl_xor(rs, 1);
            rs += __shfl_xor(rs, 2);
            rs += __shfl_xor(rs, 4);
            rs += __shfl_xor(rs, 8);
            lrun[r] = lrun[r] * alpha + rs;
            #pragma unroll
            for (int dt = 0; dt < 4; ++dt) oacc[dt][r] *= alpha;
        }

        #pragma unroll
        for (int nt = 0; nt < 4; ++nt)
            #pragma unroll
            for (int r = 0; r < 4; ++r)
                lp[wv][qd*4 + r][nt*16 + c16] = __float2bfloat16(pval[nt][r]);
        bf16x8 pf[2];
        #pragma unroll
        for (int kh = 0; kh < 2; ++kh)
            pf[kh] = *(const bf16x8*)&lp[wv][c16][kh*32 + qd*8];

        #pragma unroll
        for (int dt = 0; dt < 4; ++dt) {
            #pragma unroll
            for (int kh = 0; kh < 2; ++kh) {
                bf16x8 vf = *(const bf16x8*)&lvt[dt*16 + c16][kh*32 + qd*8];
                oacc[dt] = __builtin_amdgcn_mfma_f32_16x16x32_bf16(pf[kh], vf, oacc[dt], 0, 0, 0);
            }
        }
    }

    #pragma unroll
    for (int r = 0; r < 4; ++r) {
        float inv = 1.0f / lrun[r];
        float* dst = op + (size_t)(q0 + wv*16 + qd*4 + r) * D;
        #pragma unroll
        for (int dt = 0; dt < 4; ++dt)
            dst[dt*16 + c16] = oacc[dt][r] * inv;
    }
}

extern "C" void kernel_launch(void* const* d_in, const int* in_sizes, int n_in,
                              void* d_out, int out_size, void* d_ws, size_t ws_size,
                              hipStream_t stream) {
    const float* q = (const float*)d_in[0];
    const float* k = (const float*)d_in[1];
    const float* v = (const float*)d_in[2];
    float* out = (float*)d_out;
    const size_t elems = (size_t)BH * S * D;
    const size_t need  = 2 * elems * sizeof(short);   // Kb + VT, bf16
    if (ws_size >= need) {
        short* Kb = (short*)d_ws;
        short* VT = Kb + elems;
        preconv_25993142075924<<<dim3(S / 64, BH), 256, 0, stream>>>(k, v, Kb, VT);
        attn_fwd_v2_25993142075924<<<dim3(S / BQ, BH), 256, 0, stream>>>(q, Kb, VT, out);
    } else {
        attn_fwd_v1_25993142075924<<<dim3(S / BQ, BH), 256, 0, stream>>>(q, k, v, out);
    }
}